// Round 1
// baseline (693.342 us; speedup 1.0000x reference)
//
#include <hip/hip_runtime.h>
#include <stdint.h>

#pragma clang fp contract(off)

#define N_ELEM   1048576
#define MAX_NMS  30000
#define MAX_DET  300
#define IOU_T    0.45f
#define CONF_T   0.25f
#define SOA_N    30720

typedef uint32_t u32;

// ctrl word indices
#define C_P  0   // level-A prefix (high 16 bits of key)
#define C_K  1   // remaining K after level A
#define C_C  2   // full 32-bit cutoff key
#define C_GT 3   // cursor for keys > C
#define C_EQ 4   // count of keys == C
#define C_E  5   // number of equals to take

__device__ inline u32 monokey(float s){
  u32 b = __float_as_uint(s);
  return b ^ ((b & 0x80000000u) ? 0xFFFFFFFFu : 0x80000000u);
}
// fine bin over the valid-score key range [0xBE800000, 0xBF800000]
__device__ inline int binOf(u32 k){
  if (k < 0xBE800000u) return 0;
  u32 d = (k - 0xBE800000u) >> 8;
  return d > 65535u ? 65535 : (int)d;
}

// ---------------- kernel 1: keys + coarse 256-bin histogram ----------------
__global__ void kkeys(const float* __restrict__ pred, u32* __restrict__ keys,
                      u32* __restrict__ histA){
  __shared__ u32 h[256];
  int tid = threadIdx.x;
  h[tid] = 0; __syncthreads();
  int stride = gridDim.x * blockDim.x;
  for (int i = blockIdx.x*blockDim.x + tid; i < N_ELEM; i += stride){
    const float* row = pred + (size_t)i*7;
    float obj = row[4], c0 = row[5], c1 = row[6];
    float p0 = c0*obj, p1 = c1*obj;
    float conf = fmaxf(p0, p1);
    bool valid = (obj > CONF_T) && (conf > CONF_T);
    float score = valid ? conf : -1.0f;
    u32 mk = monokey(score);
    keys[i] = mk;
    int b = (int)(mk >> 16) - 0xBE80;
    b = b < 0 ? 0 : (b > 255 ? 255 : b);
    atomicAdd(&h[b], 1u);
  }
  __syncthreads();
  atomicAdd(&histA[tid], h[tid]);
}

// ---------------- pick level A ----------------
__global__ void kpickA(const u32* __restrict__ histA, u32* __restrict__ ctrl){
  if (threadIdx.x == 0){
    u32 K = MAX_NMS, cum = 0; int sel = 0;
    for (int b = 255; b >= 0; b--){
      u32 c = histA[b];
      if (cum + c >= K){ sel = b; break; }
      cum += c;
    }
    ctrl[C_P] = 0xBE80u + (u32)sel;
    ctrl[C_K] = K - cum;
  }
}

// ---------------- level B: fine 64K-bin histogram of low 16 bits ----------------
__global__ void khistB(const u32* __restrict__ keys, u32* __restrict__ hist64k,
                       const u32* __restrict__ ctrl){
  u32 P = ctrl[C_P];
  int stride = gridDim.x * blockDim.x;
  for (int i = blockIdx.x*blockDim.x + threadIdx.x; i < N_ELEM; i += stride){
    u32 k = keys[i];
    if ((k >> 16) == P) atomicAdd(&hist64k[k & 0xFFFFu], 1u);
  }
}

// ---------------- pick level B: exact cutoff ----------------
__global__ void kpickB(const u32* __restrict__ hist, u32* __restrict__ ctrl){
  __shared__ u32 s[1024];
  __shared__ u32 selChunk, selAbove;
  int t = threadIdx.x;
  u32 K = ctrl[C_K], P = ctrl[C_P];
  int base = t * 64;
  u32 sum = 0;
  for (int k = 0; k < 64; k++) sum += hist[base + k];
  s[t] = sum; __syncthreads();
  for (int off = 1; off < 1024; off <<= 1){
    u32 v = s[t];
    u32 add = (t + off < 1024) ? s[t + off] : 0u;
    __syncthreads();
    s[t] = v + add;
    __syncthreads();
  }
  u32 incl = s[t];
  u32 above = incl - sum;
  if (above < K && K <= above + sum){ selChunk = (u32)t; selAbove = above; }
  __syncthreads();
  if (t == 0){
    int tc = (int)selChunk;
    u32 cum = selAbove, Cfull = (P << 16), E = 1;
    for (int b = 63; b >= 0; b--){
      u32 c = hist[tc*64 + b];
      if (cum + c >= K){ Cfull = (P << 16) | (u32)(tc*64 + b); E = K - cum; break; }
      cum += c;
    }
    ctrl[C_C] = Cfull; ctrl[C_E] = E;
  }
}

// ---------------- compact: greater list + equals list, fine binHist for greaters ----
__global__ void kcompact(const u32* __restrict__ keys, u32* __restrict__ ctrl,
                         u32* __restrict__ candIdx, u32* __restrict__ eqIdx,
                         u32* __restrict__ binHist){
  u32 C = ctrl[C_C];
  int stride = gridDim.x * blockDim.x;
  for (int i = blockIdx.x*blockDim.x + threadIdx.x; i < N_ELEM; i += stride){
    u32 k = keys[i];
    if (k > C){
      u32 pos = atomicAdd(&ctrl[C_GT], 1u);
      if (pos < MAX_NMS) candIdx[pos] = (u32)i;
      atomicAdd(&binHist[binOf(k)], 1u);
    } else if (k == C){
      u32 e = atomicAdd(&ctrl[C_EQ], 1u);
      if (e < 4096u) eqIdx[e] = (u32)i;
    }
  }
}

// ---------------- sort equals by index asc (bitonic), append chosen E ----------------
__global__ void keqsort(const u32* __restrict__ keys, u32* __restrict__ ctrl,
                        u32* __restrict__ candIdx, const u32* __restrict__ eqIdx,
                        u32* __restrict__ binHist){
  __shared__ u32 lds[4096];
  int t = threadIdx.x; // 256 threads
  u32 n = ctrl[C_EQ]; if (n > 4096u) n = 4096u;
  u32 E = ctrl[C_E];  if (E > 4096u) E = 4096u;
  u32 nG = ctrl[C_GT];
  for (int u = t; u < 4096; u += 256) lds[u] = (u < (int)n) ? eqIdx[u] : 0xFFFFFFFFu;
  __syncthreads();
  for (int k = 2; k <= 4096; k <<= 1){
    for (int j = k >> 1; j > 0; j >>= 1){
      for (int u = t; u < 4096; u += 256){
        int v = u ^ j;
        if (v > u){
          u32 a = lds[u], b = lds[v];
          bool up = ((u & k) == 0);
          bool sw = up ? (a > b) : (a < b);
          if (sw){ lds[u] = b; lds[v] = a; }
        }
      }
      __syncthreads();
    }
  }
  for (u32 r = (u32)t; r < E; r += 256u){
    u32 idx = lds[r];
    if (idx < N_ELEM && nG + r < MAX_NMS){
      candIdx[nG + r] = idx;
      atomicAdd(&binHist[binOf(keys[idx])], 1u);
    }
  }
}

// ---------------- suffix scan of fine bins: base = #cands in higher bins ----------------
__global__ void kscan(const u32* __restrict__ binHist, u32* __restrict__ binBase){
  __shared__ u32 s[1024];
  int t = threadIdx.x;
  int base = t * 64;
  u32 sum = 0;
  for (int k = 0; k < 64; k++) sum += binHist[base + k];
  s[t] = sum; __syncthreads();
  for (int off = 1; off < 1024; off <<= 1){
    u32 v = s[t];
    u32 add = (t + off < 1024) ? s[t + off] : 0u;
    __syncthreads();
    s[t] = v + add;
    __syncthreads();
  }
  u32 run = s[t] - sum; // count above this chunk
  for (int k = 63; k >= 0; k--){
    binBase[base + k] = run;
    run += binHist[base + k];
  }
}

// ---------------- scatter candidates into bin-ordered arrays ----------------
__global__ void kscatter(const u32* __restrict__ keys, const u32* __restrict__ candIdx,
                         const u32* __restrict__ binBase, u32* __restrict__ binCursor,
                         u32* __restrict__ binnedKey, u32* __restrict__ binnedIdx){
  int j = blockIdx.x*blockDim.x + threadIdx.x;
  if (j >= MAX_NMS) return;
  u32 i = candIdx[j]; if (i >= N_ELEM) i = 0;
  u32 k = keys[i];
  int b = binOf(k);
  u32 pos = binBase[b] + atomicAdd(&binCursor[b], 1u);
  if (pos < MAX_NMS){ binnedKey[pos] = k; binnedIdx[pos] = i; }
}

// ---------------- exact rank within bin + gather candidate data to SoA ----------------
__global__ void krank(const float* __restrict__ pred, const u32* __restrict__ binnedKey,
                      const u32* __restrict__ binnedIdx, const u32* __restrict__ binBase,
                      const u32* __restrict__ binHist, float* __restrict__ soa){
  int p = blockIdx.x*blockDim.x + threadIdx.x;
  if (p >= MAX_NMS) return;
  u32 k = binnedKey[p]; u32 i = binnedIdx[p];
  if (i >= N_ELEM) i = 0;
  int b = binOf(k);
  u32 st = binBase[b], cnt = binHist[b];
  u32 r = st;
  for (u32 q = st; q < st + cnt; q++){
    u32 kq = binnedKey[q], iq = binnedIdx[q];
    if (kq > k || (kq == k && iq < i)) r++;
  }
  if (r >= MAX_NMS) return;
  const float* row = pred + (size_t)i*7;
  float x = row[0], y = row[1], w = row[2], hh = row[3];
  float obj = row[4], c0 = row[5], c1 = row[6];
  float p0 = c0*obj, p1 = c1*obj;
  float conf = fmaxf(p0, p1);
  bool valid = (obj > CONF_T) && (conf > CONF_T);
  float score = valid ? conf : -1.0f;
  float jf = (p0 >= p1) ? 0.0f : 1.0f;
  float bx1 = x - w*0.5f, by1 = y - hh*0.5f;
  float bx2 = x + w*0.5f, by2 = y + hh*0.5f;
  float off = jf * 4096.0f;
  float ox1 = bx1 + off, oy1 = by1 + off, ox2 = bx2 + off, oy2 = by2 + off;
  float area = (ox2 - ox1) * (oy2 - oy1);
  soa[r + 0*SOA_N] = ox1;  soa[r + 1*SOA_N] = oy1;
  soa[r + 2*SOA_N] = ox2;  soa[r + 3*SOA_N] = oy2;
  soa[r + 4*SOA_N] = area; soa[r + 5*SOA_N] = score;
  soa[r + 6*SOA_N] = jf;
  soa[r + 7*SOA_N] = bx1;  soa[r + 8*SOA_N] = by1;
  soa[r + 9*SOA_N] = bx2;  soa[r +10*SOA_N] = by2;
}

// ---------------- single-wave greedy NMS walk + output ----------------
__global__ void __launch_bounds__(64) kwalk(const float* __restrict__ soa,
                                            float* __restrict__ out, int out_size){
  int tid = threadIdx.x;
  for (int o = tid; o < out_size; o += 64) out[o] = 0.0f;
  __syncthreads();
  float sx1[5], sy1[5], sx2[5], sy2[5], sa[5];
  #pragma unroll
  for (int q = 0; q < 5; q++){ sx1[q]=0.f; sy1[q]=0.f; sx2[q]=0.f; sy2[q]=0.f; sa[q]=1.f; }
  int nsel = 0; bool done = false;
  for (int base = 0; base < MAX_NMS && !done; base += 64){
    int m = min(64, MAX_NMS - base);
    int li = base + tid;
    float cox1=0.f,coy1=0.f,cox2=0.f,coy2=0.f,car=1.f,csc=-1.0f,ccl=0.f;
    float cbx1=0.f,cby1=0.f,cbx2=0.f,cby2=0.f;
    if (tid < m){
      cox1 = soa[li + 0*SOA_N]; coy1 = soa[li + 1*SOA_N];
      cox2 = soa[li + 2*SOA_N]; coy2 = soa[li + 3*SOA_N];
      car  = soa[li + 4*SOA_N]; csc  = soa[li + 5*SOA_N];
      ccl  = soa[li + 6*SOA_N];
      cbx1 = soa[li + 7*SOA_N]; cby1 = soa[li + 8*SOA_N];
      cbx2 = soa[li + 9*SOA_N]; cby2 = soa[li +10*SOA_N];
    }
    for (int t2 = 0; t2 < m; t2++){
      float sc = __shfl(csc, t2);
      if (sc <= 0.0f){ done = true; break; }
      float qx1 = __shfl(cox1, t2), qy1 = __shfl(coy1, t2);
      float qx2 = __shfl(cox2, t2), qy2 = __shfl(coy2, t2);
      float qa  = __shfl(car,  t2);
      bool supp = false;
      #pragma unroll
      for (int q = 0; q < 5; q++){
        if (tid + (q << 6) < nsel){
          float ltx = fmaxf(qx1, sx1[q]), lty = fmaxf(qy1, sy1[q]);
          float rbx = fminf(qx2, sx2[q]), rby = fminf(qy2, sy2[q]);
          float iw = fmaxf(rbx - ltx, 0.0f), ih = fmaxf(rby - lty, 0.0f);
          float inter = iw * ih;
          float iou = inter / (qa + sa[q] - inter);
          supp = supp || (iou > IOU_T);
        }
      }
      if (__any(supp)) continue;
      float bx1 = __shfl(cbx1, t2), by1 = __shfl(cby1, t2);
      float bx2 = __shfl(cbx2, t2), by2 = __shfl(cby2, t2);
      float cl  = __shfl(ccl,  t2);
      int q = nsel >> 6, ol = nsel & 63;
      if (tid == ol){
        switch (q){
          case 0: sx1[0]=qx1; sy1[0]=qy1; sx2[0]=qx2; sy2[0]=qy2; sa[0]=qa; break;
          case 1: sx1[1]=qx1; sy1[1]=qy1; sx2[1]=qx2; sy2[1]=qy2; sa[1]=qa; break;
          case 2: sx1[2]=qx1; sy1[2]=qy1; sx2[2]=qx2; sy2[2]=qy2; sa[2]=qa; break;
          case 3: sx1[3]=qx1; sy1[3]=qy1; sx2[3]=qx2; sy2[3]=qy2; sa[3]=qa; break;
          case 4: sx1[4]=qx1; sy1[4]=qy1; sx2[4]=qx2; sy2[4]=qy2; sa[4]=qa; break;
        }
      }
      if (tid == 0){
        float* dr = out + nsel*6;
        dr[0]=bx1; dr[1]=by1; dr[2]=bx2; dr[3]=by2; dr[4]=sc; dr[5]=cl;
        out[MAX_DET*6 + nsel] = 1.0f;
      }
      nsel++;
      if (nsel == MAX_DET){ done = true; break; }
    }
  }
}

extern "C" void kernel_launch(void* const* d_in, const int* in_sizes, int n_in,
                              void* d_out, int out_size, void* d_ws, size_t ws_size,
                              hipStream_t stream){
  const float* pred = (const float*)d_in[0];
  float* out = (float*)d_out;
  char* w = (char*)d_ws;
  u32* keys      = (u32*)(w + 0x000000);   // 4 MB
  u32* ctrl      = (u32*)(w + 0x400000);   // 64 words
  u32* histA     = (u32*)(w + 0x400100);   // 256 words
  u32* eqIdx     = (u32*)(w + 0x400500);   // 4096 words
  u32* candIdx   = (u32*)(w + 0x410000);   // 30000 words
  u32* hist64k   = (u32*)(w + 0x430000);   // 64K words
  u32* binHist   = (u32*)(w + 0x470000);   // 64K words
  u32* binCursor = (u32*)(w + 0x4B0000);   // 64K words
  u32* binBase   = (u32*)(w + 0x4F0000);   // 64K words
  u32* binnedKey = (u32*)(w + 0x530000);   // 30000 words
  u32* binnedIdx = (u32*)(w + 0x550000);   // 30000 words
  float* soa     = (float*)(w + 0x570000); // 11 * SOA_N floats

  hipMemsetAsync(ctrl, 0, 0x500, stream);                 // ctrl + histA
  hipMemsetAsync(hist64k, 0, 0xC0000, stream);            // hist64k + binHist + binCursor

  kkeys   <<<2048, 256, 0, stream>>>(pred, keys, histA);
  kpickA  <<<1,    64,  0, stream>>>(histA, ctrl);
  khistB  <<<2048, 256, 0, stream>>>(keys, hist64k, ctrl);
  kpickB  <<<1,    1024,0, stream>>>(hist64k, ctrl);
  kcompact<<<2048, 256, 0, stream>>>(keys, ctrl, candIdx, eqIdx, binHist);
  keqsort <<<1,    256, 0, stream>>>(keys, ctrl, candIdx, eqIdx, binHist);
  kscan   <<<1,    1024,0, stream>>>(binHist, binBase);
  kscatter<<<(MAX_NMS+255)/256, 256, 0, stream>>>(keys, candIdx, binBase, binCursor,
                                                  binnedKey, binnedIdx);
  krank   <<<(MAX_NMS+255)/256, 256, 0, stream>>>(pred, binnedKey, binnedIdx, binBase,
                                                  binHist, soa);
  kwalk   <<<1,    64,  0, stream>>>(soa, out, out_size);
}

// Round 2
// 366.085 us; speedup vs baseline: 1.8939x; 1.8939x over previous
//
#include <hip/hip_runtime.h>
#include <stdint.h>

#pragma clang fp contract(off)

#define N_ELEM   1048576
#define MAX_NMS  30000
#define MAX_DET  300
#define IOU_T    0.45f
#define CONF_T   0.25f
#define SOA_N    30720
#define KMIN     0xBE800000u
#define EQCAP    2048

typedef uint32_t u32;
typedef unsigned long long u64;

// ctrl word indices
#define C_CB   0   // cutoff bin (0xFFFFFFFF if none)
#define C_KP   1   // entries to take from cutoff bin
#define C_A    2   // count of keys strictly above cutoff bin
#define C_NUM  3   // total candidates (min(total_valid, 30000))
#define C_EQC  4   // eq-list cursor (atomic)

__device__ inline u32 monokey(float s){
  u32 b = __float_as_uint(s);
  return b ^ ((b & 0x80000000u) ? 0xFFFFFFFFu : 0x80000000u);
}
__device__ inline int binOf(u32 k){
  u32 d = (k - KMIN) >> 8;
  return d > 65535u ? 65535 : (int)d;
}
__device__ inline u64 shfl64(u64 v, int src){
  int lo = __shfl((int)(u32)(v & 0xFFFFFFFFull), src);
  int hi = __shfl((int)(u32)(v >> 32), src);
  return ((u64)(u32)hi << 32) | (u32)lo;
}

// ---- kernel 1: keys (4 rows/thread, vectorized) + 64K-bin fine histogram ----
__global__ void kkeys(const float4* __restrict__ pred4, uint4* __restrict__ keys4,
                      u32* __restrict__ hist){
  int t = blockIdx.x*blockDim.x + threadIdx.x;
  if (t >= N_ELEM/4) return;
  float4 q0 = pred4[(size_t)t*7+0], q1 = pred4[(size_t)t*7+1], q2 = pred4[(size_t)t*7+2];
  float4 q3 = pred4[(size_t)t*7+3], q4 = pred4[(size_t)t*7+4], q5 = pred4[(size_t)t*7+5];
  float4 q6 = pred4[(size_t)t*7+6];
  float f[28];
  f[0]=q0.x; f[1]=q0.y; f[2]=q0.z; f[3]=q0.w;
  f[4]=q1.x; f[5]=q1.y; f[6]=q1.z; f[7]=q1.w;
  f[8]=q2.x; f[9]=q2.y; f[10]=q2.z; f[11]=q2.w;
  f[12]=q3.x; f[13]=q3.y; f[14]=q3.z; f[15]=q3.w;
  f[16]=q4.x; f[17]=q4.y; f[18]=q4.z; f[19]=q4.w;
  f[20]=q5.x; f[21]=q5.y; f[22]=q5.z; f[23]=q5.w;
  f[24]=q6.x; f[25]=q6.y; f[26]=q6.z; f[27]=q6.w;
  u32 kk[4];
  #pragma unroll
  for (int r = 0; r < 4; r++){
    float obj = f[r*7+4], c0 = f[r*7+5], c1 = f[r*7+6];
    float p0 = c0*obj, p1 = c1*obj;
    float conf = fmaxf(p0, p1);
    bool valid = (obj > CONF_T) && (conf > CONF_T);
    float score = valid ? conf : -1.0f;
    kk[r] = monokey(score);
  }
  keys4[t] = make_uint4(kk[0], kk[1], kk[2], kk[3]);
  #pragma unroll
  for (int r = 0; r < 4; r++)
    if (kk[r] > KMIN) atomicAdd(&hist[binOf(kk[r])], 1u);
}

// ---- kernel 2: suffix-scan 64K bins, exact cutoff, binBase ----
__global__ void kbase(const u32* __restrict__ hist, u32* __restrict__ binBase,
                      u32* __restrict__ ctrl){
  __shared__ u32 s[1024];
  __shared__ int selC;
  __shared__ u32 selAbove;
  __shared__ u32 chunk[64];
  int t = threadIdx.x;
  u32 own = 0;
  #pragma unroll 8
  for (int k = 0; k < 64; k++) own += hist[t*64 + k];
  s[t] = own; __syncthreads();
  for (int off = 1; off < 1024; off <<= 1){
    u32 v = s[t];
    u32 add = (t + off < 1024) ? s[t + off] : 0u;
    __syncthreads();
    s[t] = v + add;
    __syncthreads();
  }
  u32 above = s[t] - own;
  u32 grand = s[0];
  const u32 K = MAX_NMS;
  if (grand >= K){
    if (above < K && K <= above + own){ selC = t; selAbove = above; }
  }
  __syncthreads();
  if (grand >= K && t < 64) chunk[t] = hist[selC*64 + t];
  __syncthreads();
  if (t == 0){
    if (grand < K){
      ctrl[C_CB] = 0xFFFFFFFFu; ctrl[C_KP] = 0; ctrl[C_A] = grand; ctrl[C_NUM] = grand;
    } else {
      u32 cum = selAbove;
      for (int b = 63; b >= 0; b--){
        u32 c = chunk[b];
        if (cum + c >= K){
          ctrl[C_CB] = (u32)(selC*64 + b);
          ctrl[C_KP] = K - cum;
          ctrl[C_A]  = cum;
          ctrl[C_NUM] = K;
          break;
        }
        cum += c;
      }
    }
  }
  // write binBase (count strictly above each bin)
  u32 run = above;
  for (int b = 63; b >= 0; b--){
    binBase[t*64 + b] = run;
    run += hist[t*64 + b];
  }
}

// ---- kernel 3: scatter into per-bin slots; cutoff bin -> eq list ----
__global__ void kscatter(const uint4* __restrict__ keys4, const u32* __restrict__ binBase,
                         u32* __restrict__ binCursor, u32* __restrict__ ctrl,
                         u32* __restrict__ binnedKey, u32* __restrict__ binnedIdx,
                         u32* __restrict__ eqKey, u32* __restrict__ eqIdx){
  int t = blockIdx.x*blockDim.x + threadIdx.x;
  if (t >= N_ELEM/4) return;
  int cb = (int)ctrl[C_CB];   // -1 if none
  uint4 kv = keys4[t];
  u32 kk[4] = {kv.x, kv.y, kv.z, kv.w};
  #pragma unroll
  for (int r = 0; r < 4; r++){
    u32 k = kk[r];
    if (k <= KMIN) continue;
    int b = binOf(k);
    u32 i = (u32)(t*4 + r);
    if (b > cb){
      u32 pos = binBase[b] + atomicAdd(&binCursor[b], 1u);
      if (pos < MAX_NMS){ binnedKey[pos] = k; binnedIdx[pos] = i; }
    } else if (b == cb){
      u32 e = atomicAdd(&ctrl[C_EQC], 1u);
      if (e < EQCAP){ eqKey[e] = k; eqIdx[e] = i; }
    }
  }
}

// ---- kernel 4: resolve cutoff-bin ties (tiny), place top-Kp ----
__global__ void keq(u32* __restrict__ ctrl, const u32* __restrict__ eqKey,
                    const u32* __restrict__ eqIdx, u32* __restrict__ binnedKey,
                    u32* __restrict__ binnedIdx, u32* __restrict__ binHist){
  u32 Kp = ctrl[C_KP];
  if (Kp == 0) return;
  u32 cb = ctrl[C_CB], A = ctrl[C_A];
  u32 n = ctrl[C_EQC]; if (n > EQCAP) n = EQCAP;
  int lane = threadIdx.x;
  for (u32 e = (u32)lane; e < n; e += 64){
    u32 k = eqKey[e], i = eqIdx[e];
    u32 r = 0;
    for (u32 m = 0; m < n; m++){
      u32 km = eqKey[m], im = eqIdx[m];
      r += (km > k) || (km == k && im < i);
    }
    if (r < Kp){ binnedKey[A + r] = k; binnedIdx[A + r] = i; }
  }
  if (lane == 0) binHist[cb] = Kp;   // adjust count for krank
}

// ---- kernel 5: exact rank within bin + gather to SoA ----
__global__ void krank(const float* __restrict__ pred, const u32* __restrict__ binnedKey,
                      const u32* __restrict__ binnedIdx, const u32* __restrict__ binBase,
                      const u32* __restrict__ binHist, const u32* __restrict__ ctrl,
                      float* __restrict__ soa){
  int p = blockIdx.x*blockDim.x + threadIdx.x;
  int numCand = (int)ctrl[C_NUM];
  if (p >= numCand) return;
  u32 k = binnedKey[p]; u32 i = binnedIdx[p];
  if (i >= N_ELEM) i = 0;
  int b = binOf(k);
  u32 st = binBase[b], cnt = binHist[b];
  u32 r = st;
  for (u32 q = st; q < st + cnt; q++){
    u32 kq = binnedKey[q], iq = binnedIdx[q];
    if (kq > k || (kq == k && iq < i)) r++;
  }
  if (r >= (u32)numCand) return;
  const float* row = pred + (size_t)i*7;
  float x = row[0], y = row[1], w = row[2], hh = row[3];
  float obj = row[4], c0 = row[5], c1 = row[6];
  float p0 = c0*obj, p1 = c1*obj;
  float conf = fmaxf(p0, p1);
  float jf = (p0 >= p1) ? 0.0f : 1.0f;
  float bx1 = x - w*0.5f, by1 = y - hh*0.5f;
  float bx2 = x + w*0.5f, by2 = y + hh*0.5f;
  float off = jf * 4096.0f;
  float ox1 = bx1 + off, oy1 = by1 + off, ox2 = bx2 + off, oy2 = by2 + off;
  float area = (ox2 - ox1) * (oy2 - oy1);
  soa[r + 0*SOA_N] = ox1;  soa[r + 1*SOA_N] = oy1;
  soa[r + 2*SOA_N] = ox2;  soa[r + 3*SOA_N] = oy2;
  soa[r + 4*SOA_N] = area; soa[r + 5*SOA_N] = conf;
  soa[r + 6*SOA_N] = jf;
  soa[r + 7*SOA_N] = bx1;  soa[r + 8*SOA_N] = by1;
  soa[r + 9*SOA_N] = bx2;  soa[r +10*SOA_N] = by2;
}

// ---- kernel 6: pairwise suppression mask for first W ranks ----
// wave handles 8 rows x 64 cols (one u64 word per row)
__global__ void kmask(const float* __restrict__ soa, u64* __restrict__ mask,
                      int W, int WB){
  int lane = threadIdx.x & 63;
  int gw = blockIdx.x*(blockDim.x >> 6) + (threadIdx.x >> 6);
  int rowg = gw / WB;
  int w = gw - rowg*WB;
  if (rowg*8 >= W) return;
  // triangular skip: whole word strictly below all 8 rows -> bits never needed
  if (((w + 1) << 6) <= rowg*8){
    if (lane < 8) mask[(size_t)(rowg*8 + lane)*WB + w] = 0ull;
    return;
  }
  int j = (w << 6) + lane;
  float cx1 = soa[j], cy1 = soa[j + SOA_N], cx2 = soa[j + 2*SOA_N],
        cy2 = soa[j + 3*SOA_N], ca = soa[j + 4*SOA_N];
  #pragma unroll
  for (int rr = 0; rr < 8; rr++){
    int i = rowg*8 + rr;
    float rx1 = soa[i], ry1 = soa[i + SOA_N], rx2 = soa[i + 2*SOA_N],
          ry2 = soa[i + 3*SOA_N], ra = soa[i + 4*SOA_N];
    float ltx = fmaxf(rx1, cx1), lty = fmaxf(ry1, cy1);
    float rbx = fminf(rx2, cx2), rby = fminf(ry2, cy2);
    float iw = fmaxf(rbx - ltx, 0.0f), ih = fmaxf(rby - lty, 0.0f);
    float inter = iw * ih;
    float iou = inter / ((ra + ca) - inter);
    u64 m = __ballot(iou > IOU_T);
    if (lane == 0) mask[(size_t)i*WB + w] = m;
  }
}

// ---- kernel 7: single-wave mask walk (+ shfl fallback past window) ----
__global__ void __launch_bounds__(64) kwalk(const float* __restrict__ soa,
                                            const u64* __restrict__ mask,
                                            const u32* __restrict__ ctrl,
                                            float* __restrict__ out, int out_size,
                                            int W){
  __shared__ float kx1[320], ky1[320], kx2[320], ky2[320], ka[320];
  int lane = threadIdx.x;
  for (int o = lane; o < out_size; o += 64) out[o] = 0.0f;
  int numCand = (int)ctrl[C_NUM];
  int WB = W >> 6;
  int lim = numCand < W ? numCand : W;
  u64 rem0 = 0, rem1 = 0;
  int nsel = 0;
  int nb = (lim + 63) >> 6;
  for (int bi = 0; bi < nb && nsel < MAX_DET; bi++){
    u64 w = ~(bi < 64 ? shfl64(rem0, bi) : shfl64(rem1, bi - 64));
    int rb = lim - (bi << 6);
    if (rb < 64) w &= ((1ull << rb) - 1ull);
    while (w){
      int b = (int)__builtin_ctzll(w);
      int i = (bi << 6) + b;
      u64 r0 = (lane < WB) ? mask[(size_t)i*WB + lane] : 0ull;
      u64 r1 = (WB == 128) ? mask[(size_t)i*WB + 64 + lane] : 0ull;
      if (lane == 0){
        float ox1 = soa[i], oy1 = soa[i + SOA_N], ox2 = soa[i + 2*SOA_N],
              oy2 = soa[i + 3*SOA_N], ar = soa[i + 4*SOA_N];
        kx1[nsel] = ox1; ky1[nsel] = oy1; kx2[nsel] = ox2; ky2[nsel] = oy2; ka[nsel] = ar;
        float bx1 = soa[i + 7*SOA_N], by1 = soa[i + 8*SOA_N];
        float bx2 = soa[i + 9*SOA_N], by2 = soa[i + 10*SOA_N];
        float sc = soa[i + 5*SOA_N], cl = soa[i + 6*SOA_N];
        float* dr = out + nsel*6;
        dr[0] = bx1; dr[1] = by1; dr[2] = bx2; dr[3] = by2; dr[4] = sc; dr[5] = cl;
        out[MAX_DET*6 + nsel] = 1.0f;
      }
      rem0 |= r0; rem1 |= r1;
      u64 rw = (bi < 64) ? shfl64(r0, bi) : shfl64(r1, bi - 64);
      w &= ~rw;
      w &= ~(1ull << b);
      nsel++;
      if (nsel == MAX_DET) break;
    }
  }
  // fallback: ranks [W, numCand) via shfl walk against LDS kept list
  if (nsel < MAX_DET && numCand > W){
    for (int base = W; base < numCand && nsel < MAX_DET; base += 64){
      int li = base + lane;
      bool has = li < numCand;
      float cox1=0.f,coy1=0.f,cox2=0.f,coy2=0.f,car=1.f,csc=-1.f,ccl=0.f;
      float cbx1=0.f,cby1=0.f,cbx2=0.f,cby2=0.f;
      if (has){
        cox1 = soa[li]; coy1 = soa[li + SOA_N]; cox2 = soa[li + 2*SOA_N];
        coy2 = soa[li + 3*SOA_N]; car = soa[li + 4*SOA_N];
        csc = soa[li + 5*SOA_N]; ccl = soa[li + 6*SOA_N];
        cbx1 = soa[li + 7*SOA_N]; cby1 = soa[li + 8*SOA_N];
        cbx2 = soa[li + 9*SOA_N]; cby2 = soa[li + 10*SOA_N];
      }
      int m = min(64, numCand - base);
      for (int t2 = 0; t2 < m && nsel < MAX_DET; t2++){
        float qx1 = __shfl(cox1, t2), qy1 = __shfl(coy1, t2);
        float qx2 = __shfl(cox2, t2), qy2 = __shfl(coy2, t2);
        float qa  = __shfl(car,  t2);
        bool supp = false;
        #pragma unroll
        for (int q = 0; q < 5; q++){
          int slot = lane + (q << 6);
          if (slot < nsel){
            float ltx = fmaxf(qx1, kx1[slot]), lty = fmaxf(qy1, ky1[slot]);
            float rbx = fminf(qx2, kx2[slot]), rby = fminf(qy2, ky2[slot]);
            float iw = fmaxf(rbx - ltx, 0.0f), ih = fmaxf(rby - lty, 0.0f);
            float inter = iw * ih;
            float iou = inter / ((qa + ka[slot]) - inter);
            supp = supp || (iou > IOU_T);
          }
        }
        if (__any(supp)) continue;
        float bx1 = __shfl(cbx1, t2), by1 = __shfl(cby1, t2);
        float bx2 = __shfl(cbx2, t2), by2 = __shfl(cby2, t2);
        float sc  = __shfl(csc,  t2), cl  = __shfl(ccl,  t2);
        if (lane == 0){
          kx1[nsel] = qx1; ky1[nsel] = qy1; kx2[nsel] = qx2; ky2[nsel] = qy2; ka[nsel] = qa;
          float* dr = out + nsel*6;
          dr[0] = bx1; dr[1] = by1; dr[2] = bx2; dr[3] = by2; dr[4] = sc; dr[5] = cl;
          out[MAX_DET*6 + nsel] = 1.0f;
        }
        nsel++;
      }
    }
  }
}

extern "C" void kernel_launch(void* const* d_in, const int* in_sizes, int n_in,
                              void* d_out, int out_size, void* d_ws, size_t ws_size,
                              hipStream_t stream){
  const float* pred = (const float*)d_in[0];
  float* out = (float*)d_out;
  char* w = (char*)d_ws;

  u32*  keys      = (u32*)(w + 0x000000);   // 4 MB
  u32*  hist      = (u32*)(w + 0x400000);   // 256 KB
  u32*  binCursor = (u32*)(w + 0x440000);   // 256 KB
  u32*  ctrl      = (u32*)(w + 0x480000);   // 256 B
  u32*  binBase   = (u32*)(w + 0x4C0000);   // 256 KB
  u32*  eqKey     = (u32*)(w + 0x500000);   // 8 KB
  u32*  eqIdx     = (u32*)(w + 0x502000);   // 8 KB
  u32*  binnedKey = (u32*)(w + 0x510000);   // 120 KB
  u32*  binnedIdx = (u32*)(w + 0x530000);   // 120 KB
  float* soa      = (float*)(w + 0x550000); // 1.35 MB
  u64*  mask      = (u64*)(w + 0x6A0000);   // up to 8 MB

  // pick mask window by available workspace
  int W;
  if      (ws_size >= 0xEA0000) W = 8192;   // 8 MB mask
  else if (ws_size >= 0x8A0000) W = 4096;   // 2 MB mask
  else                          W = 2048;   // 512 KB mask
  int WB = W >> 6;

  hipMemsetAsync(hist, 0, 0x80100, stream);  // hist + binCursor + ctrl

  kkeys   <<<1024, 256, 0, stream>>>((const float4*)pred, (uint4*)keys, hist);
  kbase   <<<1, 1024, 0, stream>>>(hist, binBase, ctrl);
  kscatter<<<1024, 256, 0, stream>>>((const uint4*)keys, binBase, binCursor, ctrl,
                                     binnedKey, binnedIdx, eqKey, eqIdx);
  keq     <<<1, 64, 0, stream>>>(ctrl, eqKey, eqIdx, binnedKey, binnedIdx, hist);
  krank   <<<(MAX_NMS + 255)/256, 256, 0, stream>>>(pred, binnedKey, binnedIdx, binBase,
                                                    hist, ctrl, soa);
  int nwaves = (W/8) * WB;
  kmask   <<<(nwaves + 3)/4, 256, 0, stream>>>(soa, mask, W, WB);
  kwalk   <<<1, 64, 0, stream>>>(soa, mask, ctrl, out, out_size, W);
}

// Round 3
// 296.560 us; speedup vs baseline: 2.3379x; 1.2344x over previous
//
#include <hip/hip_runtime.h>
#include <stdint.h>

#pragma clang fp contract(off)

#define N_ELEM   1048576
#define MAX_NMS  30000
#define MAX_DET  300
#define IOU_T    0.45f
#define CONF_T   0.25f
#define SOA_N    30720
#define KMIN     0xBE800000u
#define EQCAP    2048
#define RPW      16

typedef uint32_t u32;
typedef unsigned long long u64;

// ctrl word indices
#define C_CB   0   // cutoff bin (0xFFFFFFFF if none)
#define C_KP   1   // entries to take from cutoff bin
#define C_A    2   // count of keys strictly above cutoff bin
#define C_NUM  3   // total candidates (min(total_valid, 30000))
#define C_EQC  4   // eq-list cursor (atomic)

__device__ inline u32 monokey(float s){
  u32 b = __float_as_uint(s);
  return b ^ ((b & 0x80000000u) ? 0xFFFFFFFFu : 0x80000000u);
}
__device__ inline int binOf(u32 k){
  u32 d = (k - KMIN) >> 8;
  return d > 65535u ? 65535 : (int)d;
}
__device__ inline u64 shfl64(u64 v, int src){
  int lo = __shfl((int)(u32)(v & 0xFFFFFFFFull), src);
  int hi = __shfl((int)(u32)(v >> 32), src);
  return ((u64)(u32)hi << 32) | (u32)lo;
}

// ---- kernel 1: keys (4 rows/thread, vectorized) + 64K-bin fine histogram ----
__global__ void kkeys(const float4* __restrict__ pred4, uint4* __restrict__ keys4,
                      u32* __restrict__ hist){
  int t = blockIdx.x*blockDim.x + threadIdx.x;
  if (t >= N_ELEM/4) return;
  float4 q0 = pred4[(size_t)t*7+0], q1 = pred4[(size_t)t*7+1], q2 = pred4[(size_t)t*7+2];
  float4 q3 = pred4[(size_t)t*7+3], q4 = pred4[(size_t)t*7+4], q5 = pred4[(size_t)t*7+5];
  float4 q6 = pred4[(size_t)t*7+6];
  float f[28];
  f[0]=q0.x; f[1]=q0.y; f[2]=q0.z; f[3]=q0.w;
  f[4]=q1.x; f[5]=q1.y; f[6]=q1.z; f[7]=q1.w;
  f[8]=q2.x; f[9]=q2.y; f[10]=q2.z; f[11]=q2.w;
  f[12]=q3.x; f[13]=q3.y; f[14]=q3.z; f[15]=q3.w;
  f[16]=q4.x; f[17]=q4.y; f[18]=q4.z; f[19]=q4.w;
  f[20]=q5.x; f[21]=q5.y; f[22]=q5.z; f[23]=q5.w;
  f[24]=q6.x; f[25]=q6.y; f[26]=q6.z; f[27]=q6.w;
  u32 kk[4];
  #pragma unroll
  for (int r = 0; r < 4; r++){
    float obj = f[r*7+4], c0 = f[r*7+5], c1 = f[r*7+6];
    float p0 = c0*obj, p1 = c1*obj;
    float conf = fmaxf(p0, p1);
    bool valid = (obj > CONF_T) && (conf > CONF_T);
    float score = valid ? conf : -1.0f;
    kk[r] = monokey(score);
  }
  keys4[t] = make_uint4(kk[0], kk[1], kk[2], kk[3]);
  #pragma unroll
  for (int r = 0; r < 4; r++)
    if (kk[r] > KMIN) atomicAdd(&hist[binOf(kk[r])], 1u);
}

// ---- kernel 2: suffix-scan 64K bins, exact cutoff, binBase ----
__global__ void kbase(const u32* __restrict__ hist, u32* __restrict__ binBase,
                      u32* __restrict__ ctrl){
  __shared__ u32 s[1024];
  __shared__ int selC;
  __shared__ u32 selAbove;
  __shared__ u32 chunk[64];
  int t = threadIdx.x;
  u32 own = 0;
  #pragma unroll 8
  for (int k = 0; k < 64; k++) own += hist[t*64 + k];
  s[t] = own; __syncthreads();
  for (int off = 1; off < 1024; off <<= 1){
    u32 v = s[t];
    u32 add = (t + off < 1024) ? s[t + off] : 0u;
    __syncthreads();
    s[t] = v + add;
    __syncthreads();
  }
  u32 above = s[t] - own;
  u32 grand = s[0];
  const u32 K = MAX_NMS;
  if (grand >= K){
    if (above < K && K <= above + own){ selC = t; selAbove = above; }
  }
  __syncthreads();
  if (grand >= K && t < 64) chunk[t] = hist[selC*64 + t];
  __syncthreads();
  if (t == 0){
    if (grand < K){
      ctrl[C_CB] = 0xFFFFFFFFu; ctrl[C_KP] = 0; ctrl[C_A] = grand; ctrl[C_NUM] = grand;
    } else {
      u32 cum = selAbove;
      for (int b = 63; b >= 0; b--){
        u32 c = chunk[b];
        if (cum + c >= K){
          ctrl[C_CB] = (u32)(selC*64 + b);
          ctrl[C_KP] = K - cum;
          ctrl[C_A]  = cum;
          ctrl[C_NUM] = K;
          break;
        }
        cum += c;
      }
    }
  }
  u32 run = above;
  for (int b = 63; b >= 0; b--){
    binBase[t*64 + b] = run;
    run += hist[t*64 + b];
  }
}

// ---- kernel 3: scatter into per-bin slots; cutoff bin -> eq list ----
__global__ void kscatter(const uint4* __restrict__ keys4, const u32* __restrict__ binBase,
                         u32* __restrict__ binCursor, u32* __restrict__ ctrl,
                         u32* __restrict__ binnedKey, u32* __restrict__ binnedIdx,
                         u32* __restrict__ eqKey, u32* __restrict__ eqIdx){
  int t = blockIdx.x*blockDim.x + threadIdx.x;
  if (t >= N_ELEM/4) return;
  int cb = (int)ctrl[C_CB];
  uint4 kv = keys4[t];
  u32 kk[4] = {kv.x, kv.y, kv.z, kv.w};
  #pragma unroll
  for (int r = 0; r < 4; r++){
    u32 k = kk[r];
    if (k <= KMIN) continue;
    int b = binOf(k);
    u32 i = (u32)(t*4 + r);
    if (b > cb){
      u32 pos = binBase[b] + atomicAdd(&binCursor[b], 1u);
      if (pos < MAX_NMS){ binnedKey[pos] = k; binnedIdx[pos] = i; }
    } else if (b == cb){
      u32 e = atomicAdd(&ctrl[C_EQC], 1u);
      if (e < EQCAP){ eqKey[e] = k; eqIdx[e] = i; }
    }
  }
}

// ---- kernel 4: resolve cutoff-bin ties, place top-Kp ----
__global__ void keq(u32* __restrict__ ctrl, const u32* __restrict__ eqKey,
                    const u32* __restrict__ eqIdx, u32* __restrict__ binnedKey,
                    u32* __restrict__ binnedIdx, u32* __restrict__ binHist){
  u32 Kp = ctrl[C_KP];
  if (Kp == 0) return;
  u32 cb = ctrl[C_CB], A = ctrl[C_A];
  u32 n = ctrl[C_EQC]; if (n > EQCAP) n = EQCAP;
  int lane = threadIdx.x;
  for (u32 e = (u32)lane; e < n; e += 64){
    u32 k = eqKey[e], i = eqIdx[e];
    u32 r = 0;
    for (u32 m = 0; m < n; m++){
      u32 km = eqKey[m], im = eqIdx[m];
      r += (km > k) || (km == k && im < i);
    }
    if (r < Kp){ binnedKey[A + r] = k; binnedIdx[A + r] = i; }
  }
  if (lane == 0) binHist[cb] = Kp;
}

// ---- kernel 5: exact rank within bin + gather to SoA ----
__global__ void krank(const float* __restrict__ pred, const u32* __restrict__ binnedKey,
                      const u32* __restrict__ binnedIdx, const u32* __restrict__ binBase,
                      const u32* __restrict__ binHist, const u32* __restrict__ ctrl,
                      float* __restrict__ soa){
  int p = blockIdx.x*blockDim.x + threadIdx.x;
  int numCand = (int)ctrl[C_NUM];
  if (p >= numCand) return;
  u32 k = binnedKey[p]; u32 i = binnedIdx[p];
  if (i >= N_ELEM) i = 0;
  int b = binOf(k);
  u32 st = binBase[b], cnt = binHist[b];
  u32 r = st;
  for (u32 q = st; q < st + cnt; q++){
    u32 kq = binnedKey[q], iq = binnedIdx[q];
    if (kq > k || (kq == k && iq < i)) r++;
  }
  if (r >= (u32)numCand) return;
  const float* row = pred + (size_t)i*7;
  float x = row[0], y = row[1], w = row[2], hh = row[3];
  float obj = row[4], c0 = row[5], c1 = row[6];
  float p0 = c0*obj, p1 = c1*obj;
  float conf = fmaxf(p0, p1);
  float jf = (p0 >= p1) ? 0.0f : 1.0f;
  float bx1 = x - w*0.5f, by1 = y - hh*0.5f;
  float bx2 = x + w*0.5f, by2 = y + hh*0.5f;
  float off = jf * 4096.0f;
  float ox1 = bx1 + off, oy1 = by1 + off, ox2 = bx2 + off, oy2 = by2 + off;
  float area = (ox2 - ox1) * (oy2 - oy1);
  soa[r + 0*SOA_N] = ox1;  soa[r + 1*SOA_N] = oy1;
  soa[r + 2*SOA_N] = ox2;  soa[r + 3*SOA_N] = oy2;
  soa[r + 4*SOA_N] = area; soa[r + 5*SOA_N] = conf;
  soa[r + 6*SOA_N] = jf;
  soa[r + 7*SOA_N] = bx1;  soa[r + 8*SOA_N] = by1;
  soa[r + 9*SOA_N] = bx2;  soa[r +10*SOA_N] = by2;
}

// ---- kernel 6: pairwise mask, upper-triangle words only, 16 rows/wave ----
// Words strictly below a row's diagonal word are NEVER written (the walk
// provably never consumes those bits), saving half the work + traffic.
__global__ void kmask(const float* __restrict__ soa, u64* __restrict__ mask,
                      int W, int WB){
  int lane = threadIdx.x & 63;
  int gw = blockIdx.x*(blockDim.x >> 6) + (threadIdx.x >> 6);
  int nRowG = W / RPW;
  int rowg = gw / WB;
  int w = gw - rowg*WB;
  if (rowg >= nRowG) return;
  if (((w + 1) << 6) <= rowg*RPW) return;   // whole word below all rows in group
  int j = (w << 6) + lane;
  float cx1 = soa[j], cy1 = soa[j + SOA_N], cx2 = soa[j + 2*SOA_N],
        cy2 = soa[j + 3*SOA_N], ca = soa[j + 4*SOA_N];
  #pragma unroll
  for (int rr = 0; rr < RPW; rr++){
    int i = rowg*RPW + rr;
    if (w < (i >> 6)) continue;             // word strictly below row i: skip
    float rx1 = soa[i], ry1 = soa[i + SOA_N], rx2 = soa[i + 2*SOA_N],
          ry2 = soa[i + 3*SOA_N], ra = soa[i + 4*SOA_N];
    float ltx = fmaxf(rx1, cx1), lty = fmaxf(ry1, cy1);
    float rbx = fminf(rx2, cx2), rby = fminf(ry2, cy2);
    float iw = fmaxf(rbx - ltx, 0.0f), ih = fmaxf(rby - lty, 0.0f);
    float inter = iw * ih;
    float iou = inter / ((ra + ca) - inter);
    u64 m = __ballot(iou > IOU_T);
    if (lane == 0) mask[(size_t)i*WB + w] = m;
  }
}

// ---- kernel 7: word-at-a-time mask walk ----
__global__ void __launch_bounds__(64) kwalk(const float* __restrict__ soa,
                                            const u64* __restrict__ mask,
                                            const u32* __restrict__ ctrl,
                                            float* __restrict__ out, int out_size,
                                            int W){
  __shared__ float kx1[320], ky1[320], kx2[320], ky2[320], ka[320];
  int lane = threadIdx.x;
  for (int o = lane; o < out_size; o += 64) out[o] = 0.0f;
  int numCand = (int)ctrl[C_NUM];
  int WB = W >> 6;
  int lim = numCand < W ? numCand : W;
  int nb = (lim + 63) >> 6;
  u64 rem0 = 0, rem1 = 0;
  int nsel = 0;

  // prefetch diagonal word for word 0: lane l -> row l, word 0
  u64 diag = 0;
  if (nb > 0 && lane < lim) diag = mask[(size_t)lane*WB + 0];

  for (int bi = 0; bi < nb && nsel < MAX_DET; bi++){
    u64 remw = (bi < 64) ? shfl64(rem0, bi) : shfl64(rem1, bi - 64);
    u64 w = ~remw;
    int rb = lim - (bi << 6);
    if (rb < 64) w &= ((1ull << rb) - 1ull);
    u64 mydiag = diag;

    // prefetch next word's diagonal
    u64 diagn = 0;
    int inext = (bi + 1)*64 + lane;
    if (bi + 1 < nb && inext < lim) diagn = mask[(size_t)inext*WB + (bi + 1)];

    // serial intra-word resolve — registers only
    u64 sel = 0;
    int room = MAX_DET - nsel;
    while (w){
      int b = (int)__builtin_ctzll(w);
      sel |= (1ull << b);
      if (--room == 0) break;
      u64 rw = shfl64(mydiag, b);
      w &= ~rw;
      w &= ~(1ull << b);
    }
    int cnt = __popcll(sel);

    // parallel output + kept-list write: lane j handles j-th set bit
    if (lane < cnt){
      u64 t = sel;
      for (int q = 0; q < lane; q++) t &= t - 1;
      int b = (int)__builtin_ctzll(t);
      int i = (bi << 6) + b;
      int r = nsel + lane;
      kx1[r] = soa[i];            ky1[r] = soa[i + SOA_N];
      kx2[r] = soa[i + 2*SOA_N];  ky2[r] = soa[i + 3*SOA_N];
      ka[r]  = soa[i + 4*SOA_N];
      float* dr = out + r*6;
      dr[0] = soa[i + 7*SOA_N];  dr[1] = soa[i + 8*SOA_N];
      dr[2] = soa[i + 9*SOA_N];  dr[3] = soa[i + 10*SOA_N];
      dr[4] = soa[i + 5*SOA_N];  dr[5] = soa[i + 6*SOA_N];
      out[MAX_DET*6 + r] = 1.0f;
    }
    nsel += cnt;

    // bulk rem update: all selected rows loaded in parallel (batch of 8)
    u64 s = sel;
    while (s){
      long long ids[8];
      #pragma unroll
      for (int q = 0; q < 8; q++){
        if (s){ ids[q] = (long long)((bi << 6) + __builtin_ctzll(s)); s &= s - 1; }
        else ids[q] = -1;
      }
      u64 a0[8], a1[8];
      #pragma unroll
      for (int q = 0; q < 8; q++){
        a0[q] = 0; a1[q] = 0;
        if (ids[q] >= 0){
          const u64* rp = mask + (size_t)ids[q]*WB;
          if (lane < WB)      a0[q] = rp[lane];
          if (64 + lane < WB) a1[q] = rp[64 + lane];
        }
      }
      #pragma unroll
      for (int q = 0; q < 8; q++){ rem0 |= a0[q]; rem1 |= a1[q]; }
    }
    diag = diagn;
  }

  // fallback: ranks [W, numCand) via shfl walk against LDS kept list
  if (nsel < MAX_DET && numCand > W){
    for (int base = W; base < numCand && nsel < MAX_DET; base += 64){
      int li = base + lane;
      bool has = li < numCand;
      float cox1=0.f,coy1=0.f,cox2=0.f,coy2=0.f,car=1.f,csc=-1.f,ccl=0.f;
      float cbx1=0.f,cby1=0.f,cbx2=0.f,cby2=0.f;
      if (has){
        cox1 = soa[li]; coy1 = soa[li + SOA_N]; cox2 = soa[li + 2*SOA_N];
        coy2 = soa[li + 3*SOA_N]; car = soa[li + 4*SOA_N];
        csc = soa[li + 5*SOA_N]; ccl = soa[li + 6*SOA_N];
        cbx1 = soa[li + 7*SOA_N]; cby1 = soa[li + 8*SOA_N];
        cbx2 = soa[li + 9*SOA_N]; cby2 = soa[li + 10*SOA_N];
      }
      int m = min(64, numCand - base);
      for (int t2 = 0; t2 < m && nsel < MAX_DET; t2++){
        float qx1 = __shfl(cox1, t2), qy1 = __shfl(coy1, t2);
        float qx2 = __shfl(cox2, t2), qy2 = __shfl(coy2, t2);
        float qa  = __shfl(car,  t2);
        bool supp = false;
        #pragma unroll
        for (int q = 0; q < 5; q++){
          int slot = lane + (q << 6);
          if (slot < nsel){
            float ltx = fmaxf(qx1, kx1[slot]), lty = fmaxf(qy1, ky1[slot]);
            float rbx = fminf(qx2, kx2[slot]), rby = fminf(qy2, ky2[slot]);
            float iw = fmaxf(rbx - ltx, 0.0f), ih = fmaxf(rby - lty, 0.0f);
            float inter = iw * ih;
            float iou = inter / ((qa + ka[slot]) - inter);
            supp = supp || (iou > IOU_T);
          }
        }
        if (__any(supp)) continue;
        float bx1 = __shfl(cbx1, t2), by1 = __shfl(cby1, t2);
        float bx2 = __shfl(cbx2, t2), by2 = __shfl(cby2, t2);
        float sc  = __shfl(csc,  t2), cl  = __shfl(ccl,  t2);
        if (lane == 0){
          kx1[nsel] = qx1; ky1[nsel] = qy1; kx2[nsel] = qx2; ky2[nsel] = qy2; ka[nsel] = qa;
          float* dr = out + nsel*6;
          dr[0] = bx1; dr[1] = by1; dr[2] = bx2; dr[3] = by2; dr[4] = sc; dr[5] = cl;
          out[MAX_DET*6 + nsel] = 1.0f;
        }
        nsel++;
      }
    }
  }
}

extern "C" void kernel_launch(void* const* d_in, const int* in_sizes, int n_in,
                              void* d_out, int out_size, void* d_ws, size_t ws_size,
                              hipStream_t stream){
  const float* pred = (const float*)d_in[0];
  float* out = (float*)d_out;
  char* w = (char*)d_ws;

  u32*  keys      = (u32*)(w + 0x000000);   // 4 MB
  u32*  hist      = (u32*)(w + 0x400000);   // 256 KB
  u32*  binCursor = (u32*)(w + 0x440000);   // 256 KB
  u32*  ctrl      = (u32*)(w + 0x480000);   // 256 B
  u32*  binBase   = (u32*)(w + 0x4C0000);   // 256 KB
  u32*  eqKey     = (u32*)(w + 0x500000);   // 8 KB
  u32*  eqIdx     = (u32*)(w + 0x502000);   // 8 KB
  u32*  binnedKey = (u32*)(w + 0x510000);   // 120 KB
  u32*  binnedIdx = (u32*)(w + 0x530000);   // 120 KB
  float* soa      = (float*)(w + 0x550000); // 1.35 MB
  u64*  mask      = (u64*)(w + 0x6A0000);   // up to 8 MB

  int W;
  if      (ws_size >= 0xEA0000) W = 8192;   // 8 MB mask
  else if (ws_size >= 0x8A0000) W = 4096;   // 2 MB mask
  else                          W = 2048;   // 512 KB mask
  int WB = W >> 6;

  hipMemsetAsync(hist, 0, 0x80100, stream);  // hist + binCursor + ctrl

  kkeys   <<<1024, 256, 0, stream>>>((const float4*)pred, (uint4*)keys, hist);
  kbase   <<<1, 1024, 0, stream>>>(hist, binBase, ctrl);
  kscatter<<<1024, 256, 0, stream>>>((const uint4*)keys, binBase, binCursor, ctrl,
                                     binnedKey, binnedIdx, eqKey, eqIdx);
  keq     <<<1, 64, 0, stream>>>(ctrl, eqKey, eqIdx, binnedKey, binnedIdx, hist);
  krank   <<<(MAX_NMS + 255)/256, 256, 0, stream>>>(pred, binnedKey, binnedIdx, binBase,
                                                    hist, ctrl, soa);
  int nwaves = (W/RPW) * WB;
  kmask   <<<(nwaves + 3)/4, 256, 0, stream>>>(soa, mask, W, WB);
  kwalk   <<<1, 64, 0, stream>>>(soa, mask, ctrl, out, out_size, W);
}

// Round 5
// 285.891 us; speedup vs baseline: 2.4252x; 1.0373x over previous
//
#include <hip/hip_runtime.h>
#include <stdint.h>

#pragma clang fp contract(off)

#define N_ELEM   1048576
#define MAX_NMS  30000
#define MAX_DET  300
#define IOU_T    0.45f
#define CONF_T   0.25f
#define SOA_N    30720
#define KMIN     0xBE800000u
#define EQCAP    2048
#define RPW      16

typedef uint32_t u32;
typedef unsigned long long u64;

// ctrl word indices
#define C_CB   0   // cutoff bin (0xFFFFFFFF if none)
#define C_KP   1   // entries to take from cutoff bin
#define C_A    2   // count of keys strictly above cutoff bin
#define C_NUM  3   // total candidates (min(total_valid, 30000))
#define C_EQC  4   // eq-list cursor (atomic)

__device__ inline u32 monokey(float s){
  u32 b = __float_as_uint(s);
  return b ^ ((b & 0x80000000u) ? 0xFFFFFFFFu : 0x80000000u);
}
__device__ inline int binOf(u32 k){
  u32 d = (k - KMIN) >> 8;
  return d > 65535u ? 65535 : (int)d;
}
__device__ inline u64 shfl64(u64 v, int src){
  int lo = __shfl((int)(u32)(v & 0xFFFFFFFFull), src);
  int hi = __shfl((int)(u32)(v >> 32), src);
  return ((u64)(u32)hi << 32) | (u32)lo;
}

// ---- kernel 1: LDS-staged keys (coalesced 28MB read) + 64K-bin histogram ----
__global__ void kkeys(const float4* __restrict__ pred4, u32* __restrict__ keys,
                      u32* __restrict__ hist){
  __shared__ float lds[1792];             // 256 rows x 7 floats
  int t = threadIdx.x;
  const float4* src = pred4 + (size_t)blockIdx.x * 448;
  float4* l4 = (float4*)lds;
  #pragma unroll
  for (int k = 0; k < 2; k++){
    int idx = k*256 + t;
    if (idx < 448) l4[idx] = src[idx];
  }
  __syncthreads();
  float obj = lds[t*7 + 4], c0 = lds[t*7 + 5], c1 = lds[t*7 + 6];
  float p0 = c0*obj, p1 = c1*obj;
  float conf = fmaxf(p0, p1);
  bool valid = (obj > CONF_T) && (conf > CONF_T);
  float score = valid ? conf : -1.0f;
  u32 mk = monokey(score);
  keys[blockIdx.x*256 + t] = mk;
  if (mk > KMIN) atomicAdd(&hist[binOf(mk)], 1u);
}

// ---- kernel 2a: per-chunk sums (1024 chunks, one wave each, coalesced) ----
__global__ void kchunks(const u32* __restrict__ hist, u32* __restrict__ chunkSum){
  int gw = (blockIdx.x*blockDim.x + threadIdx.x) >> 6;
  int lane = threadIdx.x & 63;
  if (gw >= 1024) return;
  u32 v = hist[gw*64 + lane];
  #pragma unroll
  for (int off = 32; off > 0; off >>= 1) v += __shfl_down(v, off);
  if (lane == 0) chunkSum[gw] = v;
}

// ---- kernel 2b: chunk suffix-scan, exact cutoff, chunkAbove ----
__global__ void kpick(const u32* __restrict__ chunkSum, const u32* __restrict__ hist,
                      u32* __restrict__ chunkAbove, u32* __restrict__ ctrl){
  __shared__ u32 s[1024];
  __shared__ int selC;
  __shared__ u32 selAbove;
  __shared__ u32 chunk[64];
  int t = threadIdx.x;
  u32 own = chunkSum[t];
  s[t] = own; __syncthreads();
  for (int off = 1; off < 1024; off <<= 1){
    u32 v = s[t];
    u32 add = (t + off < 1024) ? s[t + off] : 0u;
    __syncthreads();
    s[t] = v + add;
    __syncthreads();
  }
  u32 above = s[t] - own;
  chunkAbove[t] = above;
  u32 grand = s[0];
  const u32 K = MAX_NMS;
  if (grand >= K){
    if (above < K && K <= above + own){ selC = t; selAbove = above; }
  }
  __syncthreads();
  if (grand >= K && t < 64) chunk[t] = hist[selC*64 + t];
  __syncthreads();
  if (t == 0){
    if (grand < K){
      ctrl[C_CB] = 0xFFFFFFFFu; ctrl[C_KP] = 0; ctrl[C_A] = grand; ctrl[C_NUM] = grand;
    } else {
      u32 cum = selAbove;
      for (int b = 63; b >= 0; b--){
        u32 c = chunk[b];
        if (cum + c >= K){
          ctrl[C_CB] = (u32)(selC*64 + b);
          ctrl[C_KP] = K - cum;
          ctrl[C_A]  = cum;
          ctrl[C_NUM] = K;
          break;
        }
        cum += c;
      }
    }
  }
}

// ---- kernel 2c: binBase via per-chunk wave suffix-scan (coalesced) ----
__global__ void kbinbase(const u32* __restrict__ hist, const u32* __restrict__ chunkAbove,
                         u32* __restrict__ binBase){
  int gw = (blockIdx.x*blockDim.x + threadIdx.x) >> 6;
  int lane = threadIdx.x & 63;
  if (gw >= 1024) return;
  u32 v = hist[gw*64 + lane];
  u32 suf = v;
  #pragma unroll
  for (int off = 1; off < 64; off <<= 1){
    u32 o = __shfl_down(suf, off);
    suf += (lane + off < 64) ? o : 0u;
  }
  binBase[gw*64 + lane] = chunkAbove[gw] + suf - v;   // count strictly above bin
}

// ---- kernel 3: scatter into per-bin slots; cutoff bin -> eq list ----
__global__ void kscatter(const uint4* __restrict__ keys4, const u32* __restrict__ binBase,
                         u32* __restrict__ binCursor, u32* __restrict__ ctrl,
                         u32* __restrict__ binnedKey, u32* __restrict__ binnedIdx,
                         u32* __restrict__ eqKey, u32* __restrict__ eqIdx){
  int t = blockIdx.x*blockDim.x + threadIdx.x;
  if (t >= N_ELEM/4) return;
  int cb = (int)ctrl[C_CB];
  uint4 kv = keys4[t];
  u32 kk[4] = {kv.x, kv.y, kv.z, kv.w};
  #pragma unroll
  for (int r = 0; r < 4; r++){
    u32 k = kk[r];
    if (k <= KMIN) continue;
    int b = binOf(k);
    u32 i = (u32)(t*4 + r);
    if (b > cb){
      u32 pos = binBase[b] + atomicAdd(&binCursor[b], 1u);
      if (pos < MAX_NMS){ binnedKey[pos] = k; binnedIdx[pos] = i; }
    } else if (b == cb){
      u32 e = atomicAdd(&ctrl[C_EQC], 1u);
      if (e < EQCAP){ eqKey[e] = k; eqIdx[e] = i; }
    }
  }
}

// ---- kernel 4: resolve cutoff-bin ties, place top-Kp ----
__global__ void keq(u32* __restrict__ ctrl, const u32* __restrict__ eqKey,
                    const u32* __restrict__ eqIdx, u32* __restrict__ binnedKey,
                    u32* __restrict__ binnedIdx, u32* __restrict__ binHist){
  u32 Kp = ctrl[C_KP];
  if (Kp == 0) return;
  u32 cb = ctrl[C_CB], A = ctrl[C_A];
  u32 n = ctrl[C_EQC]; if (n > EQCAP) n = EQCAP;
  int lane = threadIdx.x;
  for (u32 e = (u32)lane; e < n; e += 64){
    u32 k = eqKey[e], i = eqIdx[e];
    u32 r = 0;
    for (u32 m = 0; m < n; m++){
      u32 km = eqKey[m], im = eqIdx[m];
      r += (km > k) || (km == k && im < i);
    }
    if (r < Kp){ binnedKey[A + r] = k; binnedIdx[A + r] = i; }
  }
  if (lane == 0) binHist[cb] = Kp;
}

// ---- kernel 5: exact rank within bin + gather to SoA ----
__global__ void krank(const float* __restrict__ pred, const u32* __restrict__ binnedKey,
                      const u32* __restrict__ binnedIdx, const u32* __restrict__ binBase,
                      const u32* __restrict__ binHist, const u32* __restrict__ ctrl,
                      float* __restrict__ soa){
  int p = blockIdx.x*blockDim.x + threadIdx.x;
  int numCand = (int)ctrl[C_NUM];
  if (p >= numCand) return;
  u32 k = binnedKey[p]; u32 i = binnedIdx[p];
  if (i >= N_ELEM) i = 0;
  int b = binOf(k);
  u32 st = binBase[b], cnt = binHist[b];
  u32 r = st;
  for (u32 q = st; q < st + cnt; q++){
    u32 kq = binnedKey[q], iq = binnedIdx[q];
    if (kq > k || (kq == k && iq < i)) r++;
  }
  if (r >= (u32)numCand) return;
  const float* row = pred + (size_t)i*7;
  float x = row[0], y = row[1], w = row[2], hh = row[3];
  float obj = row[4], c0 = row[5], c1 = row[6];
  float p0 = c0*obj, p1 = c1*obj;
  float conf = fmaxf(p0, p1);
  float jf = (p0 >= p1) ? 0.0f : 1.0f;
  float bx1 = x - w*0.5f, by1 = y - hh*0.5f;
  float bx2 = x + w*0.5f, by2 = y + hh*0.5f;
  float off = jf * 4096.0f;
  float ox1 = bx1 + off, oy1 = by1 + off, ox2 = bx2 + off, oy2 = by2 + off;
  float area = (ox2 - ox1) * (oy2 - oy1);
  soa[r + 0*SOA_N] = ox1;  soa[r + 1*SOA_N] = oy1;
  soa[r + 2*SOA_N] = ox2;  soa[r + 3*SOA_N] = oy2;
  soa[r + 4*SOA_N] = area; soa[r + 5*SOA_N] = conf;
  soa[r + 6*SOA_N] = jf;
  soa[r + 7*SOA_N] = bx1;  soa[r + 8*SOA_N] = by1;
  soa[r + 9*SOA_N] = bx2;  soa[r +10*SOA_N] = by2;
}

// ---- kernel 6: pairwise mask, upper-triangle, grid-stride (fixed small grid) ----
__global__ void kmask(const float* __restrict__ soa, u64* __restrict__ mask,
                      int W, int WBsh, int nUnits){
  int lane = threadIdx.x & 63;
  int gw = (blockIdx.x*blockDim.x + threadIdx.x) >> 6;
  int nwaves = (gridDim.x*blockDim.x) >> 6;
  int WB = 1 << WBsh;
  for (int u = gw; u < nUnits; u += nwaves){
    int rowg = u >> WBsh;
    int w = u & (WB - 1);
    if (((w + 1) << 6) <= rowg*RPW) continue;   // whole word below all rows in group
    int j = (w << 6) + lane;
    float cx1 = soa[j], cy1 = soa[j + SOA_N], cx2 = soa[j + 2*SOA_N],
          cy2 = soa[j + 3*SOA_N], ca = soa[j + 4*SOA_N];
    #pragma unroll
    for (int rr = 0; rr < RPW; rr++){
      int i = rowg*RPW + rr;
      if (w < (i >> 6)) continue;               // word strictly below row i: skip
      float rx1 = soa[i], ry1 = soa[i + SOA_N], rx2 = soa[i + 2*SOA_N],
            ry2 = soa[i + 3*SOA_N], ra = soa[i + 4*SOA_N];
      float ltx = fmaxf(rx1, cx1), lty = fmaxf(ry1, cy1);
      float rbx = fminf(rx2, cx2), rby = fminf(ry2, cy2);
      float iw = fmaxf(rbx - ltx, 0.0f), ih = fmaxf(rby - lty, 0.0f);
      float inter = iw * ih;
      float iou = inter / ((ra + ca) - inter);
      u64 m = __ballot(iou > IOU_T);
      if (lane == 0) mask[(size_t)i*WB + w] = m;
    }
  }
}

// ---- kernel 7: word-at-a-time mask walk (LDS diag resolve) ----
__global__ void __launch_bounds__(64) kwalk(const float* __restrict__ soa,
                                            const u64* __restrict__ mask,
                                            const u32* __restrict__ ctrl,
                                            float* __restrict__ out, int out_size,
                                            int W){
  __shared__ float kx1[320], ky1[320], kx2[320], ky2[320], ka[320];
  __shared__ u64 dlds[64];
  int lane = threadIdx.x;
  for (int o = lane; o < out_size; o += 64) out[o] = 0.0f;
  int numCand = (int)ctrl[C_NUM];
  int WB = W >> 6;
  int lim = numCand < W ? numCand : W;
  int nb = (lim + 63) >> 6;
  u64 rem0 = 0, rem1 = 0;
  int nsel = 0;

  // prefetch diagonal word for word 0: lane l -> row l, word 0
  u64 diag = 0;
  if (nb > 0 && lane < lim) diag = mask[(size_t)lane*WB + 0];

  for (int bi = 0; bi < nb && nsel < MAX_DET; bi++){
    u64 remw = (bi < 64) ? shfl64(rem0, bi) : shfl64(rem1, bi - 64);
    u64 w = ~remw;
    int rb = lim - (bi << 6);
    if (rb < 64) w &= ((1ull << rb) - 1ull);
    dlds[lane] = diag;
    __syncthreads();

    // prefetch next word's diagonal
    u64 diagn = 0;
    int inext = (bi + 1)*64 + lane;
    if (bi + 1 < nb && inext < lim) diagn = mask[(size_t)inext*WB + (bi + 1)];

    // serial intra-word resolve — LDS broadcast reads
    u64 sel = 0;
    int room = MAX_DET - nsel;
    while (w){
      int b = (int)__builtin_ctzll(w);
      sel |= (1ull << b);
      if (--room == 0) break;
      u64 rw = dlds[b];
      w &= ~rw;
      w &= ~(1ull << b);
    }
    int cnt = __popcll(sel);

    // issue first batch of row loads (covers typical cnt<=8), overlap with outputs
    u64 s = sel;
    long long ids[8];
    #pragma unroll
    for (int q = 0; q < 8; q++){
      if (s){ ids[q] = (long long)((bi << 6) + __builtin_ctzll(s)); s &= s - 1; }
      else ids[q] = -1;
    }
    u64 a0[8], a1[8];
    #pragma unroll
    for (int q = 0; q < 8; q++){
      a0[q] = 0; a1[q] = 0;
      if (ids[q] >= 0){
        const u64* rp = mask + (size_t)ids[q]*WB;
        if (lane < WB)      a0[q] = rp[lane];
        if (64 + lane < WB) a1[q] = rp[64 + lane];
      }
    }

    // parallel output + kept-list write: lane j handles j-th set bit
    if (lane < cnt){
      u64 t = sel;
      for (int q = 0; q < lane; q++) t &= t - 1;
      int b = (int)__builtin_ctzll(t);
      int i = (bi << 6) + b;
      int r = nsel + lane;
      kx1[r] = soa[i];            ky1[r] = soa[i + SOA_N];
      kx2[r] = soa[i + 2*SOA_N];  ky2[r] = soa[i + 3*SOA_N];
      ka[r]  = soa[i + 4*SOA_N];
      float* dr = out + r*6;
      dr[0] = soa[i + 7*SOA_N];  dr[1] = soa[i + 8*SOA_N];
      dr[2] = soa[i + 9*SOA_N];  dr[3] = soa[i + 10*SOA_N];
      dr[4] = soa[i + 5*SOA_N];  dr[5] = soa[i + 6*SOA_N];
      out[MAX_DET*6 + r] = 1.0f;
    }
    nsel += cnt;

    #pragma unroll
    for (int q = 0; q < 8; q++){ rem0 |= a0[q]; rem1 |= a1[q]; }

    // rare overflow batches (cnt > 8)
    while (s){
      long long ids2[8];
      #pragma unroll
      for (int q = 0; q < 8; q++){
        if (s){ ids2[q] = (long long)((bi << 6) + __builtin_ctzll(s)); s &= s - 1; }
        else ids2[q] = -1;
      }
      u64 b0[8], b1[8];
      #pragma unroll
      for (int q = 0; q < 8; q++){
        b0[q] = 0; b1[q] = 0;
        if (ids2[q] >= 0){
          const u64* rp = mask + (size_t)ids2[q]*WB;
          if (lane < WB)      b0[q] = rp[lane];
          if (64 + lane < WB) b1[q] = rp[64 + lane];
        }
      }
      #pragma unroll
      for (int q = 0; q < 8; q++){ rem0 |= b0[q]; rem1 |= b1[q]; }
    }
    diag = diagn;
    __syncthreads();
  }

  // fallback: ranks [W, numCand) via shfl walk against LDS kept list
  if (nsel < MAX_DET && numCand > W){
    for (int base = W; base < numCand && nsel < MAX_DET; base += 64){
      int li = base + lane;
      bool has = li < numCand;
      float cox1=0.f,coy1=0.f,cox2=0.f,coy2=0.f,car=1.f,csc=-1.f,ccl=0.f;
      float cbx1=0.f,cby1=0.f,cbx2=0.f,cby2=0.f;
      if (has){
        cox1 = soa[li]; coy1 = soa[li + SOA_N]; cox2 = soa[li + 2*SOA_N];
        coy2 = soa[li + 3*SOA_N]; car = soa[li + 4*SOA_N];
        csc = soa[li + 5*SOA_N]; ccl = soa[li + 6*SOA_N];
        cbx1 = soa[li + 7*SOA_N]; cby1 = soa[li + 8*SOA_N];
        cbx2 = soa[li + 9*SOA_N]; cby2 = soa[li + 10*SOA_N];
      }
      int m = min(64, numCand - base);
      for (int t2 = 0; t2 < m && nsel < MAX_DET; t2++){
        float qx1 = __shfl(cox1, t2), qy1 = __shfl(coy1, t2);
        float qx2 = __shfl(cox2, t2), qy2 = __shfl(coy2, t2);
        float qa  = __shfl(car,  t2);
        bool supp = false;
        #pragma unroll
        for (int q = 0; q < 5; q++){
          int slot = lane + (q << 6);
          if (slot < nsel){
            float ltx = fmaxf(qx1, kx1[slot]), lty = fmaxf(qy1, ky1[slot]);
            float rbx = fminf(qx2, kx2[slot]), rby = fminf(qy2, ky2[slot]);
            float iw = fmaxf(rbx - ltx, 0.0f), ih = fmaxf(rby - lty, 0.0f);
            float inter = iw * ih;
            float iou = inter / ((qa + ka[slot]) - inter);
            supp = supp || (iou > IOU_T);
          }
        }
        if (__any(supp)) continue;
        float bx1 = __shfl(cbx1, t2), by1 = __shfl(cby1, t2);
        float bx2 = __shfl(cbx2, t2), by2 = __shfl(cby2, t2);
        float sc  = __shfl(csc,  t2), cl  = __shfl(ccl,  t2);
        if (lane == 0){
          kx1[nsel] = qx1; ky1[nsel] = qy1; kx2[nsel] = qx2; ky2[nsel] = qy2; ka[nsel] = qa;
          float* dr = out + nsel*6;
          dr[0] = bx1; dr[1] = by1; dr[2] = bx2; dr[3] = by2; dr[4] = sc; dr[5] = cl;
          out[MAX_DET*6 + nsel] = 1.0f;
        }
        nsel++;
      }
    }
  }
}

extern "C" void kernel_launch(void* const* d_in, const int* in_sizes, int n_in,
                              void* d_out, int out_size, void* d_ws, size_t ws_size,
                              hipStream_t stream){
  const float* pred = (const float*)d_in[0];
  float* out = (float*)d_out;
  char* w = (char*)d_ws;

  u32*  keys       = (u32*)(w + 0x000000);   // 4 MB
  u32*  hist       = (u32*)(w + 0x400000);   // 256 KB
  u32*  binCursor  = (u32*)(w + 0x440000);   // 256 KB
  u32*  ctrl       = (u32*)(w + 0x480000);   // 256 B
  u32*  chunkSum   = (u32*)(w + 0x484000);   // 4 KB
  u32*  chunkAbove = (u32*)(w + 0x488000);   // 4 KB
  u32*  binBase    = (u32*)(w + 0x4C0000);   // 256 KB
  u32*  eqKey      = (u32*)(w + 0x500000);   // 8 KB
  u32*  eqIdx      = (u32*)(w + 0x502000);   // 8 KB
  u32*  binnedKey  = (u32*)(w + 0x510000);   // 120 KB
  u32*  binnedIdx  = (u32*)(w + 0x530000);   // 120 KB
  float* soa       = (float*)(w + 0x550000); // 1.35 MB
  u64*  mask       = (u64*)(w + 0x6A0000);   // up to 8 MB

  int W, WBsh;
  if      (ws_size >= 0xEA0000){ W = 8192; WBsh = 7; }
  else if (ws_size >= 0x8A0000){ W = 4096; WBsh = 6; }
  else                         { W = 2048; WBsh = 5; }

  hipMemsetAsync(hist, 0, 0x80100, stream);  // hist + binCursor + ctrl

  kkeys   <<<4096, 256, 0, stream>>>((const float4*)pred, keys, hist);
  kchunks <<<256, 256, 0, stream>>>(hist, chunkSum);
  kpick   <<<1, 1024, 0, stream>>>(chunkSum, hist, chunkAbove, ctrl);
  kbinbase<<<256, 256, 0, stream>>>(hist, chunkAbove, binBase);
  kscatter<<<1024, 256, 0, stream>>>((const uint4*)keys, binBase, binCursor, ctrl,
                                     binnedKey, binnedIdx, eqKey, eqIdx);
  keq     <<<1, 64, 0, stream>>>(ctrl, eqKey, eqIdx, binnedKey, binnedIdx, hist);
  krank   <<<(MAX_NMS + 255)/256, 256, 0, stream>>>(pred, binnedKey, binnedIdx, binBase,
                                                    hist, ctrl, soa);
  int nUnits = (W/RPW) << WBsh;
  kmask   <<<2048, 256, 0, stream>>>(soa, mask, W, WBsh, nUnits);
  kwalk   <<<1, 64, 0, stream>>>(soa, mask, ctrl, out, out_size, W);
}